// Round 1
// baseline (1119.809 us; speedup 1.0000x reference)
//
#include <hip/hip_runtime.h>
#include <hip/hip_bf16.h>

// Problem: B=8, L=16384, d=256, K=8, G=L/K=2048
// outputs: queries (B,L,d) f32 = 33554432 elems, final_state (B,d) = 2048 elems
#define EPSV 1e-8f

typedef __attribute__((ext_vector_type(4))) float f32x4;
typedef __attribute__((ext_vector_type(8))) __bf16 bf16x8;
typedef __attribute__((ext_vector_type(8))) unsigned short ushort8;

static __device__ __forceinline__ unsigned short f2bf(float x) {
    __hip_bfloat16 h = __float2bfloat16(x);   // RNE
    return *reinterpret_cast<unsigned short*>(&h);
}
static __device__ __forceinline__ float bf2f(unsigned short u) {
    __hip_bfloat16 h = *reinterpret_cast<__hip_bfloat16*>(&u);
    return __bfloat162float(h);
}

// ---------------------------------------------------------------------------
// K0: build B'^T: for each output-col e (row of W_q), 768 bf16 entries:
//   j in [0,256):  hi(Wq[e][j])
//   j in [256,512): lo(Wq[e][j-256])
//   j in [512,768): hi(Wq[e][j-512])
// layout bpt[e*768 + j]  (row-major per e → GEMM stages with vector loads)
__global__ __launch_bounds__(256) void build_bpt_kernel(const float* __restrict__ wq,
                                                        unsigned short* __restrict__ bpt) {
    int idx = blockIdx.x * 256 + threadIdx.x;          // 768*256 = 196608 total
    int e = idx / 768;
    int j = idx - e * 768;
    int d = j & 255;
    int band = j >> 8;
    float w = wq[e * 256 + d];
    unsigned short hi = f2bf(w);
    unsigned short v;
    if (band == 1) v = f2bf(w - bf2f(hi));             // lo
    else           v = hi;
    bpt[idx] = v;
}

// ---------------------------------------------------------------------------
// K1: per (b,g): gv = l2norm(mean_k(token[b,g,k,:]*lp[k,:]));
//     v[b,g,:] = (1-alpha) * gv * mp[g,:]
// one block (256 threads) per group; thread t = dim d
__global__ __launch_bounds__(256) void groupvec_kernel(const float* __restrict__ tv,
                                                       const float* __restrict__ lp,
                                                       const float* __restrict__ mp,
                                                       const float* __restrict__ dl,
                                                       float* __restrict__ v) {
    int bid = blockIdx.x;              // b*2048 + g
    int g = bid & 2047;
    int d = threadIdx.x;
    const float* base = tv + (size_t)bid * 2048 + d;   // bid*8*256
    float acc = 0.f;
#pragma unroll
    for (int k = 0; k < 8; ++k)
        acc += base[k * 256] * lp[k * 256 + d];
    float m = acc * 0.125f;

    // block-wide sum of m^2
    float p = m * m;
#pragma unroll
    for (int s = 1; s < 64; s <<= 1) p += __shfl_xor(p, s);
    __shared__ float red[4];
    if ((threadIdx.x & 63) == 0) red[threadIdx.x >> 6] = p;
    __syncthreads();
    float tot = red[0] + red[1] + red[2] + red[3];
    float n = sqrtf(tot);
    float inv = 1.0f / fmaxf(n, EPSV);

    float alpha = 1.0f / (1.0f + expf(-dl[d]));
    v[(size_t)bid * 256 + d] = (1.0f - alpha) * (m * inv) * mp[g * 256 + d];
}

// ---------------------------------------------------------------------------
// K2: sequential scan. 8 blocks (1/batch) x 64 lanes; lane holds dims 4l..4l+3
__global__ __launch_bounds__(64) void scan_kernel(const float* __restrict__ v,
                                                  const float* __restrict__ dl,
                                                  float* __restrict__ states,
                                                  float* __restrict__ out) {
    int b = blockIdx.x;
    int lane = threadIdx.x;
    const float* vb = v + (size_t)b * 2048 * 256 + 4 * lane;
    float* sb = states + (size_t)b * 2048 * 256 + 4 * lane;

    f32x4 alpha;
#pragma unroll
    for (int i = 0; i < 4; ++i)
        alpha[i] = 1.0f / (1.0f + expf(-dl[4 * lane + i]));

    f32x4 S = {0.f, 0.f, 0.f, 0.f};
    f32x4 vcur = *(const f32x4*)vb;
    for (int g = 0; g < 2048; ++g) {
        f32x4 vnext;
        if (g < 2047) vnext = *(const f32x4*)(vb + (size_t)(g + 1) * 256);
        else          vnext = (f32x4){0.f, 0.f, 0.f, 0.f};

        f32x4 u;
#pragma unroll
        for (int i = 0; i < 4; ++i) u[i] = fmaf(alpha[i], S[i], vcur[i]);
        float ss = u[0] * u[0] + u[1] * u[1] + u[2] * u[2] + u[3] * u[3];
#pragma unroll
        for (int s = 1; s < 64; s <<= 1) ss += __shfl_xor(ss, s);
        float n = sqrtf(ss);
        float inv = 1.0f / fmaxf(n, EPSV);
#pragma unroll
        for (int i = 0; i < 4; ++i) S[i] = u[i] * inv;

        *(f32x4*)(sb + (size_t)g * 256) = S;
        vcur = vnext;
    }
    // final_state output (after queries: offset 8*16384*256)
    *(f32x4*)(out + 33554432 + b * 256 + 4 * lane) = S;
}

// ---------------------------------------------------------------------------
// K3: queries GEMM.  C[R,e] = sum_d X[R,d]*Wq[e,d],  X[R,:] = states[b,g-1,:]*lp[k,:]
// (R = b*16384 + g*8 + k; rows with g==0 are zero)
// split-bf16: K' = 768, A bands [hi,hi,lo], B bands [hi,lo,hi]
// BM=128, BN=256(full), BK=32, 8 waves (2Mx4N), wave tile 64x64
__global__ __launch_bounds__(512) void queries_gemm_kernel(const float* __restrict__ states,
                                                           const float* __restrict__ lp,
                                                           const unsigned short* __restrict__ bpt,
                                                           float* __restrict__ out) {
    __shared__ unsigned short As[128 * 40];   // pitch 40 bf16 (80B) -> 2-way-free banks
    __shared__ unsigned short Bs[256 * 40];

    int tid = threadIdx.x;
    int lane = tid & 63;
    int wid = tid >> 6;
    int wm = wid >> 2;          // 0..1
    int wn = wid & 3;           // 0..3
    int row0 = blockIdx.x * 128;

    f32x4 acc[4][4];
#pragma unroll
    for (int i = 0; i < 4; ++i)
#pragma unroll
        for (int j = 0; j < 4; ++j) acc[i][j] = (f32x4){0.f, 0.f, 0.f, 0.f};

    // A-staging identity for this thread (fixed across chunks)
    int ar = tid >> 2;                   // 0..127
    int aj0 = (tid & 3) * 8;             // 0,8,16,24
    int R = row0 + ar;
    int ab = R >> 14;
    int al = R & 16383;
    int ag = al >> 3;
    int ak = al & 7;
    const float* srow = (ag > 0) ? (states + ((size_t)(ab * 2048 + ag - 1)) * 256) : nullptr;
    const float* lrow = lp + ak * 256;

    // B-staging identity
    int be = tid >> 1;                   // 0..255
    int bj0 = (tid & 1) * 16;            // 0 or 16

    for (int c = 0; c < 24; ++c) {
        int kc = c * 32;
        int band = c >> 3;               // 0,1 -> A hi ; 2 -> A lo
        int dc = (c & 7) * 32;

        // ---- stage A (on-the-fly X build + hi/lo split)
        {
            float vals[8];
            if (ag == 0) {
#pragma unroll
                for (int i = 0; i < 8; ++i) vals[i] = 0.f;
            } else {
                f32x4 s0 = *(const f32x4*)(srow + dc + aj0);
                f32x4 s1 = *(const f32x4*)(srow + dc + aj0 + 4);
                f32x4 l0 = *(const f32x4*)(lrow + dc + aj0);
                f32x4 l1 = *(const f32x4*)(lrow + dc + aj0 + 4);
#pragma unroll
                for (int i = 0; i < 4; ++i) { vals[i] = s0[i] * l0[i]; vals[4 + i] = s1[i] * l1[i]; }
            }
            ushort8 h;
#pragma unroll
            for (int i = 0; i < 8; ++i) {
                unsigned short hi = f2bf(vals[i]);
                h[i] = (band < 2) ? hi : f2bf(vals[i] - bf2f(hi));
            }
            *(ushort8*)&As[ar * 40 + aj0] = h;
        }
        // ---- stage B (prebuilt split, plain copy)
        {
            const unsigned short* src = bpt + (size_t)be * 768 + kc + bj0;
            ushort8 b0 = *(const ushort8*)src;
            ushort8 b1 = *(const ushort8*)(src + 8);
            *(ushort8*)&Bs[be * 40 + bj0] = b0;
            *(ushort8*)&Bs[be * 40 + bj0 + 8] = b1;
        }
        __syncthreads();

        // ---- fragments + MFMA
        int lr = lane & 15;
        int lk = (lane >> 4) * 8;
        bf16x8 af[4], bfr[4];
#pragma unroll
        for (int mi = 0; mi < 4; ++mi) {
            ushort8 r = *(const ushort8*)&As[(wm * 64 + mi * 16 + lr) * 40 + lk];
            af[mi] = __builtin_bit_cast(bf16x8, r);
        }
#pragma unroll
        for (int ni = 0; ni < 4; ++ni) {
            ushort8 r = *(const ushort8*)&Bs[(wn * 64 + ni * 16 + lr) * 40 + lk];
            bfr[ni] = __builtin_bit_cast(bf16x8, r);
        }
#pragma unroll
        for (int mi = 0; mi < 4; ++mi)
#pragma unroll
            for (int ni = 0; ni < 4; ++ni)
                acc[mi][ni] = __builtin_amdgcn_mfma_f32_16x16x32_bf16(af[mi], bfr[ni], acc[mi][ni], 0, 0, 0);
        __syncthreads();
    }

    // ---- epilogue: C row=(lane>>4)*4+q, col=lane&15
    int cr = (lane >> 4) * 4;
    int cc = lane & 15;
#pragma unroll
    for (int mi = 0; mi < 4; ++mi) {
#pragma unroll
        for (int ni = 0; ni < 4; ++ni) {
            int Rg = row0 + wm * 64 + mi * 16 + cr;
            int E = wn * 64 + ni * 16 + cc;
#pragma unroll
            for (int q = 0; q < 4; ++q)
                out[(size_t)(Rg + q) * 256 + E] = acc[mi][ni][q];
        }
    }
}

// ---------------------------------------------------------------------------
extern "C" void kernel_launch(void* const* d_in, const int* in_sizes, int n_in,
                              void* d_out, int out_size, void* d_ws, size_t ws_size,
                              hipStream_t stream) {
    const float* tv = (const float*)d_in[0];   // token_vectors (8,16384,256)
    const float* lp = (const float*)d_in[1];   // local_positions (8,256)
    const float* mp = (const float*)d_in[2];   // macro_positions (2048,256)
    const float* dl = (const float*)d_in[3];   // decay_logit (256)
    const float* wq = (const float*)d_in[4];   // W_q (256,256)
    float* out = (float*)d_out;

    float* v = (float*)d_ws;                               // 4,194,304 f32 (16 MB)
    float* states = v + 4194304;                           // 4,194,304 f32 (16 MB)
    unsigned short* bpt = (unsigned short*)(states + 4194304); // 196,608 bf16 (384 KB)

    build_bpt_kernel<<<768, 256, 0, stream>>>(wq, bpt);
    groupvec_kernel<<<16384, 256, 0, stream>>>(tv, lp, mp, dl, v);
    scan_kernel<<<8, 64, 0, stream>>>(v, dl, states, out);
    queries_gemm_kernel<<<1024, 512, 0, stream>>>(states, lp, bpt, out);
}

// Round 4
// 556.398 us; speedup vs baseline: 2.0126x; 2.0126x over previous
//
#include <hip/hip_runtime.h>
#include <hip/hip_bf16.h>

// Problem: B=8, L=16384, d=256, K=8, G=L/K=2048
// outputs: queries (B,L,d) f32 = 33554432 elems, final_state (B,d) = 2048 elems
#define EPSV 1e-8f

typedef __attribute__((ext_vector_type(4))) float f32x4;
typedef __attribute__((ext_vector_type(8))) __bf16 bf16x8;
typedef __attribute__((ext_vector_type(8))) unsigned short ushort8;

static __device__ __forceinline__ unsigned short f2bf(float x) {
    __hip_bfloat16 h = __float2bfloat16(x);   // RNE
    return *reinterpret_cast<unsigned short*>(&h);
}
static __device__ __forceinline__ float bf2f(unsigned short u) {
    __hip_bfloat16 h = *reinterpret_cast<__hip_bfloat16*>(&u);
    return __bfloat162float(h);
}

// ---- VALU-only full-wave sum, LLVM AMDGPUAtomicOptimizer sequence ---------
// 4 butterfly hops (row totals in every lane), then row_bcast15/31 accumulate
// into lane 63, then readlane 63 -> uniform scalar. No LDS pipe, no permlane.
template <int CTRL, int RMASK = 0xf>
static __device__ __forceinline__ float dpp_add(float x) {
    int y = __builtin_amdgcn_update_dpp(0, __builtin_bit_cast(int, x), CTRL, RMASK, 0xf, true);
    return x + __builtin_bit_cast(float, y);
}

static __device__ __forceinline__ float wave_allsum(float x) {
    x = dpp_add<0xB1>(x);        // quad_perm [1,0,3,2]  (xor 1)
    x = dpp_add<0x4E>(x);        // quad_perm [2,3,0,1]  (xor 2)
    x = dpp_add<0x141>(x);       // row_half_mirror      (xor 7)
    x = dpp_add<0x140>(x);       // row_mirror           (xor 15)
    x = dpp_add<0x142, 0xa>(x);  // row_bcast15 -> rows 1,3 accumulate
    x = dpp_add<0x143, 0xc>(x);  // row_bcast31 -> rows 2,3 accumulate; lane63 = total
    int t = __builtin_amdgcn_readlane(__builtin_bit_cast(int, x), 63);
    return __builtin_bit_cast(float, t);
}

// ---------------------------------------------------------------------------
// K0: build B'^T split-bf16 bands [hi, lo, hi] per output-col e
__global__ __launch_bounds__(256) void build_bpt_kernel(const float* __restrict__ wq,
                                                        unsigned short* __restrict__ bpt) {
    int idx = blockIdx.x * 256 + threadIdx.x;          // 768*256 = 196608 total
    int e = idx / 768;
    int j = idx - e * 768;
    int d = j & 255;
    int band = j >> 8;
    float w = wq[e * 256 + d];
    unsigned short hi = f2bf(w);
    unsigned short v;
    if (band == 1) v = f2bf(w - bf2f(hi));             // lo
    else           v = hi;
    bpt[idx] = v;
}

// ---------------------------------------------------------------------------
// K1: per (b,g): gv = l2norm(mean_k(token[b,g,k,:]*lp[k,:]));
//     v[b,g,:] = (1-alpha) * gv * mp[g,:]
__global__ __launch_bounds__(256) void groupvec_kernel(const float* __restrict__ tv,
                                                       const float* __restrict__ lp,
                                                       const float* __restrict__ mp,
                                                       const float* __restrict__ dl,
                                                       float* __restrict__ v) {
    int bid = blockIdx.x;              // b*2048 + g
    int g = bid & 2047;
    int d = threadIdx.x;
    const float* base = tv + (size_t)bid * 2048 + d;   // bid*8*256
    float acc = 0.f;
#pragma unroll
    for (int k = 0; k < 8; ++k)
        acc += base[k * 256] * lp[k * 256 + d];
    float m = acc * 0.125f;

    float p = m * m;
#pragma unroll
    for (int s = 1; s < 64; s <<= 1) p += __shfl_xor(p, s);
    __shared__ float red[4];
    if ((threadIdx.x & 63) == 0) red[threadIdx.x >> 6] = p;
    __syncthreads();
    float tot = red[0] + red[1] + red[2] + red[3];
    float n = sqrtf(tot);
    float inv = 1.0f / fmaxf(n, EPSV);

    float alpha = 1.0f / (1.0f + expf(-dl[d]));
    v[(size_t)bid * 256 + d] = (1.0f - alpha) * (m * inv) * mp[g * 256 + d];
}

// ---------------------------------------------------------------------------
// K2: sequential scan, latency-optimized.
// Recursion kept as (u, inv): u_g = inv_{g-1} * (alpha .* u_{g-1}) + v_g
//   - cross-lane reduce = 6 DPP adds + readlane63 (pure VALU, no LDS pipe)
//   - inv = rsq + 1 Newton step (matches sqrt+div to ~1 ulp)
//   - 16-deep statically-indexed prefetch ring for v (covers L2/HBM latency)
__global__ __launch_bounds__(64) void scan_kernel(const float* __restrict__ v,
                                                  const float* __restrict__ dl,
                                                  float* __restrict__ states,
                                                  float* __restrict__ out) {
    int b = blockIdx.x;
    int lane = threadIdx.x;
    const float* vb = v + (size_t)b * 2048 * 256 + 4 * lane;
    float* sb = states + (size_t)b * 2048 * 256 + 4 * lane;

    f32x4 alpha;
#pragma unroll
    for (int i = 0; i < 4; ++i)
        alpha[i] = 1.0f / (1.0f + expf(-dl[4 * lane + i]));

    f32x4 buf[16];
#pragma unroll
    for (int j = 0; j < 16; ++j)
        buf[j] = *(const f32x4*)(vb + (size_t)j * 256);

    f32x4 w = {0.f, 0.f, 0.f, 0.f};   // alpha .* u_prev
    float inv = 0.f;                  // 1/||u_prev|| (0 at start -> u = v)
    f32x4 S = {0.f, 0.f, 0.f, 0.f};

    for (int t = 0; t < 2048; t += 16) {
#pragma unroll
        for (int j = 0; j < 16; ++j) {
            const int g = t + j;
            f32x4 vcur = buf[j];
            const int gp = g + 16;
            if (gp < 2048) buf[j] = *(const f32x4*)(vb + (size_t)gp * 256);

            // critical path: u = inv*w + v
            f32x4 u;
#pragma unroll
            for (int i = 0; i < 4; ++i) u[i] = fmaf(inv, w[i], vcur[i]);

            // sum of squares: 2-deep tree then 6 DPP cross-lane adds
            float m01 = fmaf(u[1], u[1], u[0] * u[0]);
            float m23 = fmaf(u[3], u[3], u[2] * u[2]);
            float ss = wave_allsum(m01 + m23);

            // inv = rsqrt(max(ss, eps^2)) + 1 Newton iteration
            float ssc = fmaxf(ss, 1e-16f);
            float y0 = __builtin_amdgcn_rsqf(ssc);
            float h = 0.5f * ssc;
            float nr = fmaf(-h * y0, y0, 1.5f);
            inv = y0 * nr;

            // off critical path: next step's w, plus normalized store
#pragma unroll
            for (int i = 0; i < 4; ++i) w[i] = alpha[i] * u[i];
#pragma unroll
            for (int i = 0; i < 4; ++i) S[i] = u[i] * inv;
            *(f32x4*)(sb + (size_t)g * 256) = S;
        }
    }
    // final_state (after queries: offset 8*16384*256)
    *(f32x4*)(out + 33554432 + b * 256 + 4 * lane) = S;
}

// ---------------------------------------------------------------------------
// K3: queries GEMM.  C[R,e] = sum_d X[R,d]*Wq[e,d],  X[R,:] = states[b,g-1,:]*lp[k,:]
// split-bf16: K' = 768, A bands [hi,hi,lo], B bands [hi,lo,hi]
// BM=128, BN=256(full), BK=32, 8 waves (2Mx4N), wave tile 64x64
__global__ __launch_bounds__(512) void queries_gemm_kernel(const float* __restrict__ states,
                                                           const float* __restrict__ lp,
                                                           const unsigned short* __restrict__ bpt,
                                                           float* __restrict__ out) {
    __shared__ unsigned short As[128 * 40];   // pitch 40 bf16 (80B)
    __shared__ unsigned short Bs[256 * 40];

    int tid = threadIdx.x;
    int lane = tid & 63;
    int wid = tid >> 6;
    int wm = wid >> 2;          // 0..1
    int wn = wid & 3;           // 0..3
    int row0 = blockIdx.x * 128;

    f32x4 acc[4][4];
#pragma unroll
    for (int i = 0; i < 4; ++i)
#pragma unroll
        for (int j = 0; j < 4; ++j) acc[i][j] = (f32x4){0.f, 0.f, 0.f, 0.f};

    int ar = tid >> 2;                   // 0..127
    int aj0 = (tid & 3) * 8;             // 0,8,16,24
    int R = row0 + ar;
    int ab = R >> 14;
    int al = R & 16383;
    int ag = al >> 3;
    int ak = al & 7;
    const float* srow = (ag > 0) ? (states + ((size_t)(ab * 2048 + ag - 1)) * 256) : nullptr;
    const float* lrow = lp + ak * 256;

    int be = tid >> 1;                   // 0..255
    int bj0 = (tid & 1) * 16;            // 0 or 16

    for (int c = 0; c < 24; ++c) {
        int kc = c * 32;
        int band = c >> 3;               // 0,1 -> A hi ; 2 -> A lo
        int dc = (c & 7) * 32;

        // ---- stage A (on-the-fly X build + hi/lo split)
        {
            float vals[8];
            if (ag == 0) {
#pragma unroll
                for (int i = 0; i < 8; ++i) vals[i] = 0.f;
            } else {
                f32x4 s0 = *(const f32x4*)(srow + dc + aj0);
                f32x4 s1 = *(const f32x4*)(srow + dc + aj0 + 4);
                f32x4 l0 = *(const f32x4*)(lrow + dc + aj0);
                f32x4 l1 = *(const f32x4*)(lrow + dc + aj0 + 4);
#pragma unroll
                for (int i = 0; i < 4; ++i) { vals[i] = s0[i] * l0[i]; vals[4 + i] = s1[i] * l1[i]; }
            }
            ushort8 h;
#pragma unroll
            for (int i = 0; i < 8; ++i) {
                unsigned short hi = f2bf(vals[i]);
                h[i] = (band < 2) ? hi : f2bf(vals[i] - bf2f(hi));
            }
            *(ushort8*)&As[ar * 40 + aj0] = h;
        }
        // ---- stage B (prebuilt split, plain copy)
        {
            const unsigned short* src = bpt + (size_t)be * 768 + kc + bj0;
            ushort8 b0 = *(const ushort8*)src;
            ushort8 b1 = *(const ushort8*)(src + 8);
            *(ushort8*)&Bs[be * 40 + bj0] = b0;
            *(ushort8*)&Bs[be * 40 + bj0 + 8] = b1;
        }
        __syncthreads();

        // ---- fragments + MFMA
        int lr = lane & 15;
        int lk = (lane >> 4) * 8;
        bf16x8 af[4], bfr[4];
#pragma unroll
        for (int mi = 0; mi < 4; ++mi) {
            ushort8 r = *(const ushort8*)&As[(wm * 64 + mi * 16 + lr) * 40 + lk];
            af[mi] = __builtin_bit_cast(bf16x8, r);
        }
#pragma unroll
        for (int ni = 0; ni < 4; ++ni) {
            ushort8 r = *(const ushort8*)&Bs[(wn * 64 + ni * 16 + lr) * 40 + lk];
            bfr[ni] = __builtin_bit_cast(bf16x8, r);
        }
#pragma unroll
        for (int mi = 0; mi < 4; ++mi)
#pragma unroll
            for (int ni = 0; ni < 4; ++ni)
                acc[mi][ni] = __builtin_amdgcn_mfma_f32_16x16x32_bf16(af[mi], bfr[ni], acc[mi][ni], 0, 0, 0);
        __syncthreads();
    }

    // ---- epilogue: C row=(lane>>4)*4+q, col=lane&15
    int cr = (lane >> 4) * 4;
    int cc = lane & 15;
#pragma unroll
    for (int mi = 0; mi < 4; ++mi) {
#pragma unroll
        for (int ni = 0; ni < 4; ++ni) {
            int Rg = row0 + wm * 64 + mi * 16 + cr;
            int E = wn * 64 + ni * 16 + cc;
#pragma unroll
            for (int q = 0; q < 4; ++q)
                out[(size_t)(Rg + q) * 256 + E] = acc[mi][ni][q];
        }
    }
}

// ---------------------------------------------------------------------------
extern "C" void kernel_launch(void* const* d_in, const int* in_sizes, int n_in,
                              void* d_out, int out_size, void* d_ws, size_t ws_size,
                              hipStream_t stream) {
    const float* tv = (const float*)d_in[0];   // token_vectors (8,16384,256)
    const float* lp = (const float*)d_in[1];   // local_positions (8,256)
    const float* mp = (const float*)d_in[2];   // macro_positions (2048,256)
    const float* dl = (const float*)d_in[3];   // decay_logit (256)
    const float* wq = (const float*)d_in[4];   // W_q (256,256)
    float* out = (float*)d_out;

    float* v = (float*)d_ws;                               // 4,194,304 f32 (16 MB)
    float* states = v + 4194304;                           // 4,194,304 f32 (16 MB)
    unsigned short* bpt = (unsigned short*)(states + 4194304); // 196,608 bf16 (384 KB)

    build_bpt_kernel<<<768, 256, 0, stream>>>(wq, bpt);
    groupvec_kernel<<<16384, 256, 0, stream>>>(tv, lp, mp, dl, v);
    scan_kernel<<<8, 64, 0, stream>>>(v, dl, states, out);
    queries_gemm_kernel<<<1024, 512, 0, stream>>>(states, lp, bpt, out);
}